// Round 15
// baseline (109.105 us; speedup 1.0000x reference)
//
#include <hip/hip_runtime.h>
#include <hip/hip_bf16.h>

#define B_ 2
#define N_ 2048
#define D_ 128
#define H_ 128
#define ROWS_ (B_*N_)               // 4096
#define KS_ 16                      // key partitions
#define DMAX_ 1.4143f
#define SCALE_ 0.08838834764831845f // 1/sqrt(128)
#define LOG2E_ 1.4426950408889634f

// MEASUREMENT ROUND: attn body runs twice (idempotent). attn_single = dur/2;
// total - 48.3 ~= attn_single. Revert ATTN_REPS to 1 after reading counters.
#define ATTN_REPS 2

typedef __bf16 bf16x8 __attribute__((ext_vector_type(8)));
typedef float  f32x4  __attribute__((ext_vector_type(4)));
typedef unsigned short ushort8 __attribute__((ext_vector_type(8)));

#if __has_builtin(__builtin_amdgcn_exp2f)
#define EXP2F_ __builtin_amdgcn_exp2f
#else
#define EXP2F_ exp2f
#endif
#if __has_builtin(__builtin_amdgcn_sqrtf)
#define SQRTF_ __builtin_amdgcn_sqrtf
#else
#define SQRTF_ sqrtf
#endif

// ---- workspace layout (bytes) ----
#define Q_OFF    0
#define K_OFF    (ROWS_*H_*2)                // 1 MB each
#define V_OFF    (2*ROWS_*H_*2)
#define CF_OFF   (3*ROWS_*H_*2)              // 64 B quadratic coeffs
#define L_OFF    (CF_OFF + 64)               // l partials
#define OP_OFF   (L_OFF + ROWS_*32*4)        // u32-packed partial O (KS * 1.05 MB)

// ---------------- Kernel 1: QKV projection via MFMA (W transposed in-block) ----------------
__global__ __launch_bounds__(256) void qkv_mfma(
    const float* __restrict__ h,
    const float* __restrict__ Wq, const float* __restrict__ bq,
    const float* __restrict__ Wk, const float* __restrict__ bk,
    const float* __restrict__ Wv, const float* __restrict__ bv,
    const float* __restrict__ Wd1, const float* __restrict__ bd1,
    const float* __restrict__ Wd2, const float* __restrict__ bd2,
    __bf16* __restrict__ qb, __bf16* __restrict__ kb, __bf16* __restrict__ vb,
    float* __restrict__ cf)
{
    __shared__ __align__(16) __bf16 Wl[32][144];
    const int t = threadIdx.x;
    const int y = blockIdx.y;
    const int which = y >> 2, c0 = (y & 3) * 32;
    const float* W    = which == 0 ? Wq : (which == 1 ? Wk : Wv);
    const float* bias = which == 0 ? bq : (which == 1 ? bk : bv);
    __bf16* outp      = which == 0 ? qb : (which == 1 ? kb : vb);
    const float scale = which == 0 ? (SCALE_ * LOG2E_) : 1.f;

    if (blockIdx.x == 0 && y == 0 && t < 64) {
        const int j = t & 31;
        const float w1 = Wd1[j], b1 = bd1[j];
        const float w2h = Wd2[j] * 0.5f;
        float gv[3];
        #pragma unroll
        for (int i = 0; i < 3; ++i) {
            float d = (DMAX_ * 0.5f) * (float)i;
            float x = fmaf(d, w1, b1);
            gv[i] = (x / (1.f + __expf(-x))) * w2h;
        }
        #pragma unroll
        for (int i = 0; i < 3; ++i)
            #pragma unroll
            for (int off = 1; off < 64; off <<= 1) gv[i] += __shfl_xor(gv[i], off);
        if (t == 0) {
            const float bd2v = bd2[0];
            float g0 = (gv[0] + bd2v) * LOG2E_, g1 = (gv[1] + bd2v) * LOG2E_,
                  g2 = (gv[2] + bd2v) * LOG2E_;
            cf[0] = g0;
            cf[1] = -1.5f * g0 + 2.f * g1 - 0.5f * g2;
            cf[2] =  0.5f * g0 - g1 + 0.5f * g2;
        }
    }

    #pragma unroll
    for (int i = 0; i < 16; ++i) {
        int idx = t + i * 256, k = idx >> 5, cc = idx & 31;
        Wl[cc][k] = (__bf16)W[k * 128 + c0 + cc];
    }
    __syncthreads();

    const int wid = t >> 6, lane = t & 63, l16 = lane & 15, g = lane >> 4;
    const int row0 = blockIdx.x * 64 + wid * 16;

    bf16x8 af[4];
    const float* arow = h + (size_t)(row0 + l16) * 128;
    #pragma unroll
    for (int kk = 0; kk < 4; ++kk) {
        float4 a0 = *(const float4*)(arow + kk * 32 + g * 8);
        float4 a1 = *(const float4*)(arow + kk * 32 + g * 8 + 4);
        af[kk] = (bf16x8){ (__bf16)a0.x, (__bf16)a0.y, (__bf16)a0.z, (__bf16)a0.w,
                           (__bf16)a1.x, (__bf16)a1.y, (__bf16)a1.z, (__bf16)a1.w };
    }

    f32x4 acc0 = {0.f,0.f,0.f,0.f}, acc1 = {0.f,0.f,0.f,0.f};
    #pragma unroll
    for (int kk = 0; kk < 4; ++kk) {
        bf16x8 f0 = *(const bf16x8*)&Wl[l16][kk * 32 + g * 8];
        acc0 = __builtin_amdgcn_mfma_f32_16x16x32_bf16(af[kk], f0, acc0, 0, 0, 0);
    }
    #pragma unroll
    for (int kk = 0; kk < 4; ++kk) {
        bf16x8 f1 = *(const bf16x8*)&Wl[16 + l16][kk * 32 + g * 8];
        acc1 = __builtin_amdgcn_mfma_f32_16x16x32_bf16(af[kk], f1, acc1, 0, 0, 0);
    }
    const float bv0 = bias[c0 + l16], bv1 = bias[c0 + 16 + l16];
    #pragma unroll
    for (int i = 0; i < 4; ++i) {
        size_t r = (size_t)(row0 + g * 4 + i) * 128;
        outp[r + c0 + l16]      = (__bf16)((acc0[i] + bv0) * scale);
        outp[r + c0 + 16 + l16] = (__bf16)((acc1[i] + bv1) * scale);
    }
}

// ---------------- Kernel 2: flash attention (body repeated ATTN_REPS for profiling) ----------------
template<int KSP>
__global__ __launch_bounds__(256, 3) void attn_kernel(
    const __bf16* __restrict__ qb, const __bf16* __restrict__ kb, const __bf16* __restrict__ vb,
    const float* __restrict__ coords, const float* __restrict__ cfp,
    unsigned int* __restrict__ Opb32, float* __restrict__ Larr)
{
    constexpr int KPP = N_ / KSP;
    constexpr int NT  = KPP / 32;
    constexpr float CSC = 2.0f / DMAX_;

    __shared__ __align__(16) unsigned int Vsu[2][128][20];
    __shared__ __align__(16) __bf16 Pl[4][2][16][40];

    const int t    = threadIdx.x;
    const int wid  = t >> 6;
    const int lane = t & 63;
    const int l16  = lane & 15;
    const int g    = lane >> 4;
    const int qb0  = blockIdx.x * 128 + wid * 16;
    const int p    = blockIdx.y;
    const int b    = blockIdx.x >> 4;

    #pragma unroll 1
    for (int rep = 0; rep < ATTN_REPS; ++rep) {

    const float c0 = cfp[0], c1 = cfp[1], c2 = cfp[2];

    bf16x8 qf[2][4];
    #pragma unroll
    for (int tt = 0; tt < 2; ++tt) {
        const __bf16* qrow = qb + (size_t)(qb0 + tt * 64 + l16) * H_;
        #pragma unroll
        for (int kk = 0; kk < 4; ++kk) qf[tt][kk] = *(const bf16x8*)(qrow + kk * 32 + g * 8);
    }

    float cx[2][4], cy[2][4];
    #pragma unroll
    for (int tt = 0; tt < 2; ++tt)
        #pragma unroll
        for (int i = 0; i < 4; ++i) {
            int qr = qb0 + tt * 64 + g * 4 + i;
            cx[tt][i] = coords[qr * 2] * CSC; cy[tt][i] = coords[qr * 2 + 1] * CSC;
        }

    float l_i[2][4] = {{0.f,0.f,0.f,0.f},{0.f,0.f,0.f,0.f}};
    f32x4 O0[8], O1[8];
    #pragma unroll
    for (int c = 0; c < 8; ++c) { O0[c] = (f32x4){0.f,0.f,0.f,0.f}; O1[c] = (f32x4){0.f,0.f,0.f,0.f}; }

    const int kp = t & 15, co = t >> 4;
    const int kgbase = (b << 11) + p * KPP;

    __syncthreads();   // guard Vsu reuse across reps
    {   // stage tile 0 into buffer 0
        const __bf16* sp = vb + (size_t)(kgbase + 2 * kp) * H_ + co * 8;
        bf16x8 va = *(const bf16x8*)sp;
        bf16x8 vb2 = *(const bf16x8*)(sp + H_);
        ushort8 ua = __builtin_bit_cast(ushort8, va);
        ushort8 ub = __builtin_bit_cast(ushort8, vb2);
        #pragma unroll
        for (int j = 0; j < 8; ++j)
            Vsu[0][co * 8 + j][kp] = (unsigned)ua[j] | ((unsigned)ub[j] << 16);
    }

    for (int kt = 0; kt < NT; ++kt) {
        __syncthreads();

        bf16x8 nva, nvb;
        if (kt + 1 < NT) {
            const __bf16* sp = vb + (size_t)(kgbase + (kt + 1) * 32 + 2 * kp) * H_ + co * 8;
            nva = *(const bf16x8*)sp;
            nvb = *(const bf16x8*)(sp + H_);
        }

        const int kg = kgbase + kt * 32;
        #pragma unroll
        for (int mt = 0; mt < 2; ++mt) {
            bf16x8 kf[4];
            const __bf16* krow = kb + (size_t)(kg + mt * 16 + l16) * H_;
            #pragma unroll
            for (int kk = 0; kk < 4; ++kk) kf[kk] = *(const bf16x8*)(krow + kk * 32 + g * 8);

            f32x4 acc0 = {0.f,0.f,0.f,0.f}, acc1 = {0.f,0.f,0.f,0.f};
            #pragma unroll
            for (int kk = 0; kk < 4; ++kk)
                acc0 = __builtin_amdgcn_mfma_f32_16x16x32_bf16(qf[0][kk], kf[kk], acc0, 0, 0, 0);
            #pragma unroll
            for (int kk = 0; kk < 4; ++kk)
                acc1 = __builtin_amdgcn_mfma_f32_16x16x32_bf16(qf[1][kk], kf[kk], acc1, 0, 0, 0);

            float2 kc = *(const float2*)&coords[(kg + mt * 16 + l16) * 2];
            const float kx = kc.x * CSC, ky = kc.y * CSC;
            #pragma unroll
            for (int i = 0; i < 4; ++i) {
                float dx = cx[0][i] - kx, dy = cy[0][i] - ky;
                float s = SQRTF_(fmaf(dx, dx, fmaf(dy, dy, 2e-8f)));
                float pe = EXP2F_(acc0[i] + fmaf(fmaf(c2, s, c1), s, c0));
                l_i[0][i] += pe;
                Pl[wid][0][g * 4 + i][mt * 16 + l16] = (__bf16)pe;
            }
            #pragma unroll
            for (int i = 0; i < 4; ++i) {
                float dx = cx[1][i] - kx, dy = cy[1][i] - ky;
                float s = SQRTF_(fmaf(dx, dx, fmaf(dy, dy, 2e-8f)));
                float pe = EXP2F_(acc1[i] + fmaf(fmaf(c2, s, c1), s, c0));
                l_i[1][i] += pe;
                Pl[wid][1][g * 4 + i][mt * 16 + l16] = (__bf16)pe;
            }
        }

        if (kt + 1 < NT) {
            ushort8 ua = __builtin_bit_cast(ushort8, nva);
            ushort8 ub = __builtin_bit_cast(ushort8, nvb);
            #pragma unroll
            for (int j = 0; j < 8; ++j)
                Vsu[(kt + 1) & 1][co * 8 + j][kp] = (unsigned)ua[j] | ((unsigned)ub[j] << 16);
        }

        bf16x8 pf0 = *(const bf16x8*)&Pl[wid][0][l16][g * 8];
        bf16x8 pf1 = *(const bf16x8*)&Pl[wid][1][l16][g * 8];
        #pragma unroll
        for (int c = 0; c < 8; ++c) {
            bf16x8 vf = *(const bf16x8*)&Vsu[kt & 1][c * 16 + l16][g * 4];
            O0[c] = __builtin_amdgcn_mfma_f32_16x16x32_bf16(pf0, vf, O0[c], 0, 0, 0);
            O1[c] = __builtin_amdgcn_mfma_f32_16x16x32_bf16(pf1, vf, O1[c], 0, 0, 0);
        }
    }

    // write partials: u32-packed bf16 row-pairs (identical every rep)
    #pragma unroll
    for (int tt = 0; tt < 2; ++tt) {
        const size_t rpbase = (size_t)p * (ROWS_ / 2) + ((qb0 + tt * 64) >> 1) + g * 2;
        #pragma unroll
        for (int c = 0; c < 8; ++c)
            #pragma unroll
            for (int ip = 0; ip < 2; ++ip) {
                float lo_f = tt ? O1[c][2 * ip]     : O0[c][2 * ip];
                float hi_f = tt ? O1[c][2 * ip + 1] : O0[c][2 * ip + 1];
                unsigned lo = __builtin_bit_cast(unsigned, lo_f);
                unsigned hi = __builtin_bit_cast(unsigned, hi_f);
                Opb32[(rpbase + ip) * H_ + c * 16 + l16] = (hi & 0xffff0000u) | (lo >> 16);
            }
    }
    #pragma unroll
    for (int tt = 0; tt < 2; ++tt)
        #pragma unroll
        for (int i = 0; i < 4; ++i) {
            float lv = l_i[tt][i];
            lv += __shfl_xor(lv, 1); lv += __shfl_xor(lv, 2);
            lv += __shfl_xor(lv, 4); lv += __shfl_xor(lv, 8);
            if (l16 == 0) Larr[(qb0 + tt * 64 + g * 4 + i) * KSP + p] = lv;
        }

    }  // rep
}

// ---------------- Kernel 3: combine + out-proj + silu + residual + LN ----------------
template<int KSP>
__global__ __launch_bounds__(256) void final_kernel(
    const unsigned int* __restrict__ Opb32, const float* __restrict__ Larr,
    const float* __restrict__ h, const float* __restrict__ Wo, const float* __restrict__ bo,
    const float* __restrict__ gamma, const float* __restrict__ beta, float* __restrict__ out)
{
    __shared__ __align__(16) float as_[8][128];
    __shared__ float redS[4][4], redQ[4][4];
    const int t = threadIdx.x;
    const int c = t & 127;
    const int rh = t >> 7;
    const int bx = blockIdx.x;
    const int row0 = (bx & 31) * 128 + (bx >> 5) * 8;

    #pragma unroll
    for (int pr = 0; pr < 2; ++pr) {
        int r0 = rh * 4 + pr * 2;
        int row = row0 + r0;
        size_t rp = (size_t)row >> 1;
        float accL = 0.f, accH = 0.f, lsumL = 0.f, lsumH = 0.f;
        #pragma unroll
        for (int p = 0; p < KSP; ++p) {
            unsigned v = Opb32[((size_t)p * (ROWS_ / 2) + rp) * H_ + c];
            accL += __uint_as_float(v << 16);
            accH += __uint_as_float(v & 0xffff0000u);
        }
        #pragma unroll
        for (int q4 = 0; q4 < KSP / 4; ++q4) {
            f32x4 lL = *(const f32x4*)&Larr[row * KSP + q4 * 4];
            f32x4 lH = *(const f32x4*)&Larr[(row + 1) * KSP + q4 * 4];
            lsumL += lL[0] + lL[1] + lL[2] + lL[3];
            lsumH += lH[0] + lH[1] + lH[2] + lH[3];
        }
        as_[r0][c]     = accL / lsumL;
        as_[r0 + 1][c] = accH / lsumH;
    }
    __syncthreads();

    float acc4[4] = {0.f, 0.f, 0.f, 0.f};
    #pragma unroll 4
    for (int d4 = 0; d4 < 32; ++d4) {
        float w0 = Wo[(d4 * 4 + 0) * 128 + c];
        float w1 = Wo[(d4 * 4 + 1) * 128 + c];
        float w2 = Wo[(d4 * 4 + 2) * 128 + c];
        float w3 = Wo[(d4 * 4 + 3) * 128 + c];
        #pragma unroll
        for (int r = 0; r < 4; ++r) {
            f32x4 a_ = *(const f32x4*)&as_[rh * 4 + r][d4 * 4];
            acc4[r] = fmaf(a_[0], w0, acc4[r]);
            acc4[r] = fmaf(a_[1], w1, acc4[r]);
            acc4[r] = fmaf(a_[2], w2, acc4[r]);
            acc4[r] = fmaf(a_[3], w3, acc4[r]);
        }
    }

    const float bov = bo[c], gv = gamma[c], bvv = beta[c];
    const int wv = t >> 6;
    float res[4];
    #pragma unroll
    for (int r = 0; r < 4; ++r) {
        float x = acc4[r] + bov;
        float sl = x / (1.f + __expf(-x));
        res[r] = h[(size_t)(row0 + rh * 4 + r) * 128 + c] + sl;
    }

    #pragma unroll
    for (int r = 0; r < 4; ++r) {
        float s1 = res[r], s2 = res[r] * res[r];
        #pragma unroll
        for (int off = 32; off >= 1; off >>= 1) {
            s1 += __shfl_xor(s1, off);
            s2 += __shfl_xor(s2, off);
        }
        if ((t & 63) == 0) { redS[wv][r] = s1; redQ[wv][r] = s2; }
    }
    __syncthreads();
    #pragma unroll
    for (int r = 0; r < 4; ++r) {
        float sum = redS[2 * rh][r] + redS[2 * rh + 1][r];
        float sq  = redQ[2 * rh][r] + redQ[2 * rh + 1][r];
        float mu  = sum * (1.f / 128.f);
        float var = sq * (1.f / 128.f) - mu * mu;
        out[(size_t)(row0 + rh * 4 + r) * 128 + c] = (res[r] - mu) * rsqrtf(var + 1e-5f) * gv + bvv;
    }
}

extern "C" void kernel_launch(void* const* d_in, const int* in_sizes, int n_in,
                              void* d_out, int out_size, void* d_ws, size_t ws_size,
                              hipStream_t stream)
{
    const float* h      = (const float*)d_in[0];
    const float* coords = (const float*)d_in[1];
    const float* Wq = (const float*)d_in[2];  const float* bq = (const float*)d_in[3];
    const float* Wk = (const float*)d_in[4];  const float* bk = (const float*)d_in[5];
    const float* Wv = (const float*)d_in[6];  const float* bv = (const float*)d_in[7];
    const float* Wd1 = (const float*)d_in[8]; const float* bd1 = (const float*)d_in[9];
    const float* Wd2 = (const float*)d_in[10];const float* bd2 = (const float*)d_in[11];
    const float* Wo = (const float*)d_in[12]; const float* bo = (const float*)d_in[13];
    const float* gamma = (const float*)d_in[14]; const float* beta = (const float*)d_in[15];

    char* ws = (char*)d_ws;
    __bf16* qb = (__bf16*)(ws + Q_OFF);
    __bf16* kb = (__bf16*)(ws + K_OFF);
    __bf16* vb = (__bf16*)(ws + V_OFF);
    float* cf           = (float*)(ws + CF_OFF);
    float* Larr         = (float*)(ws + L_OFF);
    unsigned int* Opb32 = (unsigned int*)(ws + OP_OFF);

    qkv_mfma<<<dim3(64, 12), 256, 0, stream>>>(h, Wq, bq, Wk, bk, Wv, bv,
                                               Wd1, bd1, Wd2, bd2, qb, kb, vb, cf);
    attn_kernel<KS_><<<dim3(32, KS_), 256, 0, stream>>>(qb, kb, vb, coords, cf, Opb32, Larr);
    final_kernel<KS_><<<ROWS_ / 8, 256, 0, stream>>>(Opb32, Larr, h, Wo, bo, gamma, beta, (float*)d_out);
}

// Round 16
// 54.616 us; speedup vs baseline: 1.9977x; 1.9977x over previous
//
#include <hip/hip_runtime.h>
#include <hip/hip_bf16.h>

#define B_ 2
#define N_ 2048
#define D_ 128
#define H_ 128
#define ROWS_ (B_*N_)               // 4096
#define DMAX_ 1.4143f
#define SCALE_ 0.08838834764831845f // 1/sqrt(128)
#define LOG2E_ 1.4426950408889634f

typedef __bf16 bf16x8 __attribute__((ext_vector_type(8)));
typedef float  f32x4  __attribute__((ext_vector_type(4)));
typedef unsigned short ushort8 __attribute__((ext_vector_type(8)));

#if __has_builtin(__builtin_amdgcn_exp2f)
#define EXP2F_ __builtin_amdgcn_exp2f
#else
#define EXP2F_ exp2f
#endif
#if __has_builtin(__builtin_amdgcn_sqrtf)
#define SQRTF_ __builtin_amdgcn_sqrtf
#else
#define SQRTF_ sqrtf
#endif

// ---- workspace layout (bytes); OP region sized at host per ws_size ----
#define Q_OFF    0
#define K_OFF    (ROWS_*H_*2)                // 1 MB each
#define V_OFF    (2*ROWS_*H_*2)
#define CF_OFF   (3*ROWS_*H_*2)              // 64 B quadratic coeffs
#define L_OFF    (CF_OFF + 64)               // l partials (KS<=32)
#define OP_OFF   (L_OFF + ROWS_*32*4)        // u32-packed partial O (KS * 1.05 MB)

// ---------------- Kernel 1: QKV projection via MFMA (W transposed in-block) ----------------
// grid (64, 12): which = y>>2 selects q/k/v, c0 = (y&3)*32 output cols; 64 rows/block.
__global__ __launch_bounds__(256) void qkv_mfma(
    const float* __restrict__ h,
    const float* __restrict__ Wq, const float* __restrict__ bq,
    const float* __restrict__ Wk, const float* __restrict__ bk,
    const float* __restrict__ Wv, const float* __restrict__ bv,
    const float* __restrict__ Wd1, const float* __restrict__ bd1,
    const float* __restrict__ Wd2, const float* __restrict__ bd2,
    __bf16* __restrict__ qb, __bf16* __restrict__ kb, __bf16* __restrict__ vb,
    float* __restrict__ cf)
{
    __shared__ __align__(16) __bf16 Wl[32][144];
    const int t = threadIdx.x;
    const int y = blockIdx.y;
    const int which = y >> 2, c0 = (y & 3) * 32;
    const float* W    = which == 0 ? Wq : (which == 1 ? Wk : Wv);
    const float* bias = which == 0 ? bq : (which == 1 ? bk : bv);
    __bf16* outp      = which == 0 ? qb : (which == 1 ? kb : vb);
    const float scale = which == 0 ? (SCALE_ * LOG2E_) : 1.f;

    if (blockIdx.x == 0 && y == 0 && t < 64) {
        // quadratic Lagrange fit of log2e*g(d) at nodes d = {0, DMAX/2, DMAX}
        const int j = t & 31;
        const float w1 = Wd1[j], b1 = bd1[j];
        const float w2h = Wd2[j] * 0.5f;
        float gv[3];
        #pragma unroll
        for (int i = 0; i < 3; ++i) {
            float d = (DMAX_ * 0.5f) * (float)i;
            float x = fmaf(d, w1, b1);
            gv[i] = (x / (1.f + __expf(-x))) * w2h;
        }
        #pragma unroll
        for (int i = 0; i < 3; ++i)
            #pragma unroll
            for (int off = 1; off < 64; off <<= 1) gv[i] += __shfl_xor(gv[i], off);
        if (t == 0) {
            const float bd2v = bd2[0];
            float g0 = (gv[0] + bd2v) * LOG2E_, g1 = (gv[1] + bd2v) * LOG2E_,
                  g2 = (gv[2] + bd2v) * LOG2E_;
            cf[0] = g0;
            cf[1] = -1.5f * g0 + 2.f * g1 - 0.5f * g2;
            cf[2] =  0.5f * g0 - g1 + 0.5f * g2;
        }
    }

    #pragma unroll
    for (int i = 0; i < 16; ++i) {
        int idx = t + i * 256, k = idx >> 5, cc = idx & 31;
        Wl[cc][k] = (__bf16)W[k * 128 + c0 + cc];
    }
    __syncthreads();

    const int wid = t >> 6, lane = t & 63, l16 = lane & 15, g = lane >> 4;
    const int row0 = blockIdx.x * 64 + wid * 16;

    bf16x8 af[4];
    const float* arow = h + (size_t)(row0 + l16) * 128;
    #pragma unroll
    for (int kk = 0; kk < 4; ++kk) {
        float4 a0 = *(const float4*)(arow + kk * 32 + g * 8);
        float4 a1 = *(const float4*)(arow + kk * 32 + g * 8 + 4);
        af[kk] = (bf16x8){ (__bf16)a0.x, (__bf16)a0.y, (__bf16)a0.z, (__bf16)a0.w,
                           (__bf16)a1.x, (__bf16)a1.y, (__bf16)a1.z, (__bf16)a1.w };
    }

    f32x4 acc0 = {0.f,0.f,0.f,0.f}, acc1 = {0.f,0.f,0.f,0.f};
    #pragma unroll
    for (int kk = 0; kk < 4; ++kk) {
        bf16x8 f0 = *(const bf16x8*)&Wl[l16][kk * 32 + g * 8];
        acc0 = __builtin_amdgcn_mfma_f32_16x16x32_bf16(af[kk], f0, acc0, 0, 0, 0);
    }
    #pragma unroll
    for (int kk = 0; kk < 4; ++kk) {
        bf16x8 f1 = *(const bf16x8*)&Wl[16 + l16][kk * 32 + g * 8];
        acc1 = __builtin_amdgcn_mfma_f32_16x16x32_bf16(af[kk], f1, acc1, 0, 0, 0);
    }
    const float bv0 = bias[c0 + l16], bv1 = bias[c0 + 16 + l16];
    #pragma unroll
    for (int i = 0; i < 4; ++i) {
        size_t r = (size_t)(row0 + g * 4 + i) * 128;
        outp[r + c0 + l16]      = (__bf16)((acc0[i] + bv0) * scale);
        outp[r + c0 + 16 + l16] = (__bf16)((acc1[i] + bv1) * scale);
    }
}

// ---------------- Kernel 2: flash attention, 2 q-tiles per wave, templated KS ----------------
// grid (32, KSP): block owns 128 q-rows x one key partition. 3 blocks/CU (bounds-4 spilled: r11).
// Partial stores are NON-TEMPORAL (r15 PMC: partial write-stream evicted K/V from L2,
// FETCH_SIZE 145 MB vs 3 MB footprint).
template<int KSP>
__global__ __launch_bounds__(256, 3) void attn_kernel(
    const __bf16* __restrict__ qb, const __bf16* __restrict__ kb, const __bf16* __restrict__ vb,
    const float* __restrict__ coords, const float* __restrict__ cfp,
    unsigned int* __restrict__ Opb32, float* __restrict__ Larr)
{
    constexpr int KPP = N_ / KSP;
    constexpr int NT  = KPP / 32;
    constexpr float CSC = 2.0f / DMAX_;     // coord prescale; s = dist*2/DMAX

    __shared__ __align__(16) unsigned int Vsu[2][128][20];
    __shared__ __align__(16) __bf16 Pl[4][2][16][40];

    const int t    = threadIdx.x;
    const int wid  = t >> 6;
    const int lane = t & 63;
    const int l16  = lane & 15;
    const int g    = lane >> 4;
    const int qb0  = blockIdx.x * 128 + wid * 16;   // tile0 base; tile1 = +64
    const int p    = blockIdx.y;
    const int b    = blockIdx.x >> 4;               // 16 blocks per batch

    const float c0 = cfp[0], c1 = cfp[1], c2 = cfp[2];

    bf16x8 qf[2][4];
    #pragma unroll
    for (int tt = 0; tt < 2; ++tt) {
        const __bf16* qrow = qb + (size_t)(qb0 + tt * 64 + l16) * H_;
        #pragma unroll
        for (int kk = 0; kk < 4; ++kk) qf[tt][kk] = *(const bf16x8*)(qrow + kk * 32 + g * 8);
    }

    float cx[2][4], cy[2][4];
    #pragma unroll
    for (int tt = 0; tt < 2; ++tt)
        #pragma unroll
        for (int i = 0; i < 4; ++i) {
            int qr = qb0 + tt * 64 + g * 4 + i;
            cx[tt][i] = coords[qr * 2] * CSC; cy[tt][i] = coords[qr * 2 + 1] * CSC;
        }

    float l_i[2][4] = {{0.f,0.f,0.f,0.f},{0.f,0.f,0.f,0.f}};
    f32x4 O0[8], O1[8];
    #pragma unroll
    for (int c = 0; c < 8; ++c) { O0[c] = (f32x4){0.f,0.f,0.f,0.f}; O1[c] = (f32x4){0.f,0.f,0.f,0.f}; }

    const int kp = t & 15, co = t >> 4;
    const int kgbase = (b << 11) + p * KPP;

    {   // stage tile 0 into buffer 0
        const __bf16* sp = vb + (size_t)(kgbase + 2 * kp) * H_ + co * 8;
        bf16x8 va = *(const bf16x8*)sp;
        bf16x8 vb2 = *(const bf16x8*)(sp + H_);
        ushort8 ua = __builtin_bit_cast(ushort8, va);
        ushort8 ub = __builtin_bit_cast(ushort8, vb2);
        #pragma unroll
        for (int j = 0; j < 8; ++j)
            Vsu[0][co * 8 + j][kp] = (unsigned)ua[j] | ((unsigned)ub[j] << 16);
    }

    for (int kt = 0; kt < NT; ++kt) {
        __syncthreads();

        bf16x8 nva, nvb;
        if (kt + 1 < NT) {
            const __bf16* sp = vb + (size_t)(kgbase + (kt + 1) * 32 + 2 * kp) * H_ + co * 8;
            nva = *(const bf16x8*)sp;
            nvb = *(const bf16x8*)(sp + H_);
        }

        const int kg = kgbase + kt * 32;
        #pragma unroll
        for (int mt = 0; mt < 2; ++mt) {
            bf16x8 kf[4];
            const __bf16* krow = kb + (size_t)(kg + mt * 16 + l16) * H_;
            #pragma unroll
            for (int kk = 0; kk < 4; ++kk) kf[kk] = *(const bf16x8*)(krow + kk * 32 + g * 8);

            f32x4 acc0 = {0.f,0.f,0.f,0.f}, acc1 = {0.f,0.f,0.f,0.f};
            #pragma unroll
            for (int kk = 0; kk < 4; ++kk)
                acc0 = __builtin_amdgcn_mfma_f32_16x16x32_bf16(qf[0][kk], kf[kk], acc0, 0, 0, 0);
            #pragma unroll
            for (int kk = 0; kk < 4; ++kk)
                acc1 = __builtin_amdgcn_mfma_f32_16x16x32_bf16(qf[1][kk], kf[kk], acc1, 0, 0, 0);

            float2 kc = *(const float2*)&coords[(kg + mt * 16 + l16) * 2];
            const float kx = kc.x * CSC, ky = kc.y * CSC;
            #pragma unroll
            for (int i = 0; i < 4; ++i) {
                float dx = cx[0][i] - kx, dy = cy[0][i] - ky;
                float s = SQRTF_(fmaf(dx, dx, fmaf(dy, dy, 2e-8f)));
                float pe = EXP2F_(acc0[i] + fmaf(fmaf(c2, s, c1), s, c0));
                l_i[0][i] += pe;
                Pl[wid][0][g * 4 + i][mt * 16 + l16] = (__bf16)pe;
            }
            #pragma unroll
            for (int i = 0; i < 4; ++i) {
                float dx = cx[1][i] - kx, dy = cy[1][i] - ky;
                float s = SQRTF_(fmaf(dx, dx, fmaf(dy, dy, 2e-8f)));
                float pe = EXP2F_(acc1[i] + fmaf(fmaf(c2, s, c1), s, c0));
                l_i[1][i] += pe;
                Pl[wid][1][g * 4 + i][mt * 16 + l16] = (__bf16)pe;
            }
        }

        if (kt + 1 < NT) {
            ushort8 ua = __builtin_bit_cast(ushort8, nva);
            ushort8 ub = __builtin_bit_cast(ushort8, nvb);
            #pragma unroll
            for (int j = 0; j < 8; ++j)
                Vsu[(kt + 1) & 1][co * 8 + j][kp] = (unsigned)ua[j] | ((unsigned)ub[j] << 16);
        }

        bf16x8 pf0 = *(const bf16x8*)&Pl[wid][0][l16][g * 8];
        bf16x8 pf1 = *(const bf16x8*)&Pl[wid][1][l16][g * 8];
        #pragma unroll
        for (int c = 0; c < 8; ++c) {
            bf16x8 vf = *(const bf16x8*)&Vsu[kt & 1][c * 16 + l16][g * 4];
            O0[c] = __builtin_amdgcn_mfma_f32_16x16x32_bf16(pf0, vf, O0[c], 0, 0, 0);
            O1[c] = __builtin_amdgcn_mfma_f32_16x16x32_bf16(pf1, vf, O1[c], 0, 0, 0);
        }
    }

    // write partials: u32-packed bf16 row-pairs, NON-TEMPORAL (bypass L2)
    #pragma unroll
    for (int tt = 0; tt < 2; ++tt) {
        const size_t rpbase = (size_t)p * (ROWS_ / 2) + ((qb0 + tt * 64) >> 1) + g * 2;
        #pragma unroll
        for (int c = 0; c < 8; ++c)
            #pragma unroll
            for (int ip = 0; ip < 2; ++ip) {
                float lo_f = tt ? O1[c][2 * ip]     : O0[c][2 * ip];
                float hi_f = tt ? O1[c][2 * ip + 1] : O0[c][2 * ip + 1];
                unsigned lo = __builtin_bit_cast(unsigned, lo_f);
                unsigned hi = __builtin_bit_cast(unsigned, hi_f);
                __builtin_nontemporal_store((hi & 0xffff0000u) | (lo >> 16),
                                            &Opb32[(rpbase + ip) * H_ + c * 16 + l16]);
            }
    }
    #pragma unroll
    for (int tt = 0; tt < 2; ++tt)
        #pragma unroll
        for (int i = 0; i < 4; ++i) {
            float lv = l_i[tt][i];
            lv += __shfl_xor(lv, 1); lv += __shfl_xor(lv, 2);
            lv += __shfl_xor(lv, 4); lv += __shfl_xor(lv, 8);
            if (l16 == 0)
                __builtin_nontemporal_store(lv, &Larr[(qb0 + tt * 64 + g * 4 + i) * KSP + p]);
        }
}

// ---------------- Kernel 3: combine + out-proj + silu + residual + LN ----------------
template<int KSP>
__global__ __launch_bounds__(256) void final_kernel(
    const unsigned int* __restrict__ Opb32, const float* __restrict__ Larr,
    const float* __restrict__ h, const float* __restrict__ Wo, const float* __restrict__ bo,
    const float* __restrict__ gamma, const float* __restrict__ beta, float* __restrict__ out)
{
    __shared__ __align__(16) float as_[8][128];
    __shared__ float redS[4][4], redQ[4][4];
    const int t = threadIdx.x;
    const int c = t & 127;
    const int rh = t >> 7;                 // row half 0/1
    const int bx = blockIdx.x;
    const int row0 = (bx & 31) * 128 + (bx >> 5) * 8;

    // combine KSP key-partition partials (non-temporal streaming reads)
    #pragma unroll
    for (int pr = 0; pr < 2; ++pr) {
        int r0 = rh * 4 + pr * 2;          // even local row
        int row = row0 + r0;
        size_t rp = (size_t)row >> 1;
        float accL = 0.f, accH = 0.f, lsumL = 0.f, lsumH = 0.f;
        #pragma unroll
        for (int p = 0; p < KSP; ++p) {
            unsigned v = __builtin_nontemporal_load(&Opb32[((size_t)p * (ROWS_ / 2) + rp) * H_ + c]);
            accL += __uint_as_float(v << 16);
            accH += __uint_as_float(v & 0xffff0000u);
        }
        #pragma unroll
        for (int q4 = 0; q4 < KSP / 4; ++q4) {
            f32x4 lL = *(const f32x4*)&Larr[row * KSP + q4 * 4];
            f32x4 lH = *(const f32x4*)&Larr[(row + 1) * KSP + q4 * 4];
            lsumL += lL[0] + lL[1] + lL[2] + lL[3];
            lsumH += lH[0] + lH[1] + lH[2] + lH[3];
        }
        as_[r0][c]     = accL / lsumL;
        as_[r0 + 1][c] = accH / lsumH;
    }
    __syncthreads();

    // out-projection: 4 rows per thread
    float acc4[4] = {0.f, 0.f, 0.f, 0.f};
    #pragma unroll 4
    for (int d4 = 0; d4 < 32; ++d4) {
        float w0 = Wo[(d4 * 4 + 0) * 128 + c];
        float w1 = Wo[(d4 * 4 + 1) * 128 + c];
        float w2 = Wo[(d4 * 4 + 2) * 128 + c];
        float w3 = Wo[(d4 * 4 + 3) * 128 + c];
        #pragma unroll
        for (int r = 0; r < 4; ++r) {
            f32x4 a_ = *(const f32x4*)&as_[rh * 4 + r][d4 * 4];
            acc4[r] = fmaf(a_[0], w0, acc4[r]);
            acc4[r] = fmaf(a_[1], w1, acc4[r]);
            acc4[r] = fmaf(a_[2], w2, acc4[r]);
            acc4[r] = fmaf(a_[3], w3, acc4[r]);
        }
    }

    const float bov = bo[c], gv = gamma[c], bvv = beta[c];
    const int wv = t >> 6;                 // wave index 0..3
    float res[4];
    #pragma unroll
    for (int r = 0; r < 4; ++r) {
        float x = acc4[r] + bov;
        float sl = x / (1.f + __expf(-x));
        res[r] = h[(size_t)(row0 + rh * 4 + r) * 128 + c] + sl;
    }

    #pragma unroll
    for (int r = 0; r < 4; ++r) {
        float s1 = res[r], s2 = res[r] * res[r];
        #pragma unroll
        for (int off = 32; off >= 1; off >>= 1) {
            s1 += __shfl_xor(s1, off);
            s2 += __shfl_xor(s2, off);
        }
        if ((t & 63) == 0) { redS[wv][r] = s1; redQ[wv][r] = s2; }
    }
    __syncthreads();
    #pragma unroll
    for (int r = 0; r < 4; ++r) {
        float sum = redS[2 * rh][r] + redS[2 * rh + 1][r];
        float sq  = redQ[2 * rh][r] + redQ[2 * rh + 1][r];
        float mu  = sum * (1.f / 128.f);
        float var = sq * (1.f / 128.f) - mu * mu;
        out[(size_t)(row0 + rh * 4 + r) * 128 + c] = (res[r] - mu) * rsqrtf(var + 1e-5f) * gv + bvv;
    }
}

extern "C" void kernel_launch(void* const* d_in, const int* in_sizes, int n_in,
                              void* d_out, int out_size, void* d_ws, size_t ws_size,
                              hipStream_t stream)
{
    const float* h      = (const float*)d_in[0];
    const float* coords = (const float*)d_in[1];
    const float* Wq = (const float*)d_in[2];  const float* bq = (const float*)d_in[3];
    const float* Wk = (const float*)d_in[4];  const float* bk = (const float*)d_in[5];
    const float* Wv = (const float*)d_in[6];  const float* bv = (const float*)d_in[7];
    const float* Wd1 = (const float*)d_in[8]; const float* bd1 = (const float*)d_in[9];
    const float* Wd2 = (const float*)d_in[10];const float* bd2 = (const float*)d_in[11];
    const float* Wo = (const float*)d_in[12]; const float* bo = (const float*)d_in[13];
    const float* gamma = (const float*)d_in[14]; const float* beta = (const float*)d_in[15];

    char* ws = (char*)d_ws;
    __bf16* qb = (__bf16*)(ws + Q_OFF);
    __bf16* kb = (__bf16*)(ws + K_OFF);
    __bf16* vb = (__bf16*)(ws + V_OFF);
    float* cf           = (float*)(ws + CF_OFF);
    float* Larr         = (float*)(ws + L_OFF);
    unsigned int* Opb32 = (unsigned int*)(ws + OP_OFF);

    const size_t need32 = (size_t)OP_OFF + (size_t)32 * (ROWS_ / 2) * H_ * 4;
    const bool big = ws_size >= need32;

    qkv_mfma<<<dim3(64, 12), 256, 0, stream>>>(h, Wq, bq, Wk, bk, Wv, bv,
                                               Wd1, bd1, Wd2, bd2, qb, kb, vb, cf);
    if (big) {
        attn_kernel<32><<<dim3(32, 32), 256, 0, stream>>>(qb, kb, vb, coords, cf, Opb32, Larr);
        final_kernel<32><<<ROWS_ / 8, 256, 0, stream>>>(Opb32, Larr, h, Wo, bo, gamma, beta, (float*)d_out);
    } else {
        attn_kernel<16><<<dim3(32, 16), 256, 0, stream>>>(qb, kb, vb, coords, cf, Opb32, Larr);
        final_kernel<16><<<ROWS_ / 8, 256, 0, stream>>>(Opb32, Larr, h, Wo, bo, gamma, beta, (float*)d_out);
    }
}

// Round 17
// 48.306 us; speedup vs baseline: 2.2586x; 1.1306x over previous
//
#include <hip/hip_runtime.h>
#include <hip/hip_bf16.h>

#define B_ 2
#define N_ 2048
#define D_ 128
#define H_ 128
#define ROWS_ (B_*N_)               // 4096
#define DMAX_ 1.4143f
#define SCALE_ 0.08838834764831845f // 1/sqrt(128)
#define LOG2E_ 1.4426950408889634f

typedef __bf16 bf16x8 __attribute__((ext_vector_type(8)));
typedef float  f32x4  __attribute__((ext_vector_type(4)));
typedef unsigned short ushort8 __attribute__((ext_vector_type(8)));

#if __has_builtin(__builtin_amdgcn_exp2f)
#define EXP2F_ __builtin_amdgcn_exp2f
#else
#define EXP2F_ exp2f
#endif
#if __has_builtin(__builtin_amdgcn_sqrtf)
#define SQRTF_ __builtin_amdgcn_sqrtf
#else
#define SQRTF_ sqrtf
#endif

// ---- workspace layout (bytes); OP region sized at host per ws_size ----
#define Q_OFF    0
#define K_OFF    (ROWS_*H_*2)                // 1 MB each
#define V_OFF    (2*ROWS_*H_*2)
#define CF_OFF   (3*ROWS_*H_*2)              // 64 B quadratic coeffs
#define L_OFF    (CF_OFF + 64)               // l partials (KS<=32)
#define OP_OFF   (L_OFF + ROWS_*32*4)        // u32-packed partial O (KS * 1.05 MB)

// ---------------- Kernel 1: QKV projection via MFMA (W transposed in-block) ----------------
// grid (64, 12): which = y>>2 selects q/k/v, c0 = (y&3)*32 output cols; 64 rows/block.
__global__ __launch_bounds__(256) void qkv_mfma(
    const float* __restrict__ h,
    const float* __restrict__ Wq, const float* __restrict__ bq,
    const float* __restrict__ Wk, const float* __restrict__ bk,
    const float* __restrict__ Wv, const float* __restrict__ bv,
    const float* __restrict__ Wd1, const float* __restrict__ bd1,
    const float* __restrict__ Wd2, const float* __restrict__ bd2,
    __bf16* __restrict__ qb, __bf16* __restrict__ kb, __bf16* __restrict__ vb,
    float* __restrict__ cf)
{
    __shared__ __align__(16) __bf16 Wl[32][144];
    const int t = threadIdx.x;
    const int y = blockIdx.y;
    const int which = y >> 2, c0 = (y & 3) * 32;
    const float* W    = which == 0 ? Wq : (which == 1 ? Wk : Wv);
    const float* bias = which == 0 ? bq : (which == 1 ? bk : bv);
    __bf16* outp      = which == 0 ? qb : (which == 1 ? kb : vb);
    const float scale = which == 0 ? (SCALE_ * LOG2E_) : 1.f;

    if (blockIdx.x == 0 && y == 0 && t < 64) {
        // quadratic Lagrange fit of log2e*g(d) at nodes d = {0, DMAX/2, DMAX}
        const int j = t & 31;
        const float w1 = Wd1[j], b1 = bd1[j];
        const float w2h = Wd2[j] * 0.5f;
        float gv[3];
        #pragma unroll
        for (int i = 0; i < 3; ++i) {
            float d = (DMAX_ * 0.5f) * (float)i;
            float x = fmaf(d, w1, b1);
            gv[i] = (x / (1.f + __expf(-x))) * w2h;
        }
        #pragma unroll
        for (int i = 0; i < 3; ++i)
            #pragma unroll
            for (int off = 1; off < 64; off <<= 1) gv[i] += __shfl_xor(gv[i], off);
        if (t == 0) {
            const float bd2v = bd2[0];
            float g0 = (gv[0] + bd2v) * LOG2E_, g1 = (gv[1] + bd2v) * LOG2E_,
                  g2 = (gv[2] + bd2v) * LOG2E_;
            cf[0] = g0;
            cf[1] = -1.5f * g0 + 2.f * g1 - 0.5f * g2;
            cf[2] =  0.5f * g0 - g1 + 0.5f * g2;
        }
    }

    #pragma unroll
    for (int i = 0; i < 16; ++i) {
        int idx = t + i * 256, k = idx >> 5, cc = idx & 31;
        Wl[cc][k] = (__bf16)W[k * 128 + c0 + cc];
    }
    __syncthreads();

    const int wid = t >> 6, lane = t & 63, l16 = lane & 15, g = lane >> 4;
    const int row0 = blockIdx.x * 64 + wid * 16;

    bf16x8 af[4];
    const float* arow = h + (size_t)(row0 + l16) * 128;
    #pragma unroll
    for (int kk = 0; kk < 4; ++kk) {
        float4 a0 = *(const float4*)(arow + kk * 32 + g * 8);
        float4 a1 = *(const float4*)(arow + kk * 32 + g * 8 + 4);
        af[kk] = (bf16x8){ (__bf16)a0.x, (__bf16)a0.y, (__bf16)a0.z, (__bf16)a0.w,
                           (__bf16)a1.x, (__bf16)a1.y, (__bf16)a1.z, (__bf16)a1.w };
    }

    f32x4 acc0 = {0.f,0.f,0.f,0.f}, acc1 = {0.f,0.f,0.f,0.f};
    #pragma unroll
    for (int kk = 0; kk < 4; ++kk) {
        bf16x8 f0 = *(const bf16x8*)&Wl[l16][kk * 32 + g * 8];
        acc0 = __builtin_amdgcn_mfma_f32_16x16x32_bf16(af[kk], f0, acc0, 0, 0, 0);
    }
    #pragma unroll
    for (int kk = 0; kk < 4; ++kk) {
        bf16x8 f1 = *(const bf16x8*)&Wl[16 + l16][kk * 32 + g * 8];
        acc1 = __builtin_amdgcn_mfma_f32_16x16x32_bf16(af[kk], f1, acc1, 0, 0, 0);
    }
    const float bv0 = bias[c0 + l16], bv1 = bias[c0 + 16 + l16];
    #pragma unroll
    for (int i = 0; i < 4; ++i) {
        size_t r = (size_t)(row0 + g * 4 + i) * 128;
        outp[r + c0 + l16]      = (__bf16)((acc0[i] + bv0) * scale);
        outp[r + c0 + 16 + l16] = (__bf16)((acc1[i] + bv1) * scale);
    }
}

// ---------------- Kernel 2: flash attention, 2 q-tiles per wave, templated KS ----------------
// grid (KSP, 32): blockIdx.x = key partition p, blockIdx.y = q-range x.
// Linear id = p + KSP*x -> XCD = p mod 8: each K/V partition is resident on ONE
// XCD's L2 (~256 KB/XCD) and reused by all 32 q-range blocks (r15 PMC: the old
// x-mod-8 map replicated K/V into all 8 L2s -> 74 MB FETCH vs ~20 MB footprint).
template<int KSP>
__global__ __launch_bounds__(256, 3) void attn_kernel(
    const __bf16* __restrict__ qb, const __bf16* __restrict__ kb, const __bf16* __restrict__ vb,
    const float* __restrict__ coords, const float* __restrict__ cfp,
    unsigned int* __restrict__ Opb32, float* __restrict__ Larr)
{
    constexpr int KPP = N_ / KSP;
    constexpr int NT  = KPP / 32;
    constexpr float CSC = 2.0f / DMAX_;     // coord prescale; s = dist*2/DMAX

    __shared__ __align__(16) unsigned int Vsu[2][128][20];
    __shared__ __align__(16) __bf16 Pl[4][2][16][40];

    const int t    = threadIdx.x;
    const int wid  = t >> 6;
    const int lane = t & 63;
    const int l16  = lane & 15;
    const int g    = lane >> 4;
    const int xq   = blockIdx.y;                    // q-range index
    const int p    = blockIdx.x;                    // key partition
    const int qb0  = xq * 128 + wid * 16;           // tile0 base; tile1 = +64
    const int b    = xq >> 4;                       // 16 q-ranges per batch

    const float c0 = cfp[0], c1 = cfp[1], c2 = cfp[2];

    bf16x8 qf[2][4];
    #pragma unroll
    for (int tt = 0; tt < 2; ++tt) {
        const __bf16* qrow = qb + (size_t)(qb0 + tt * 64 + l16) * H_;
        #pragma unroll
        for (int kk = 0; kk < 4; ++kk) qf[tt][kk] = *(const bf16x8*)(qrow + kk * 32 + g * 8);
    }

    float cx[2][4], cy[2][4];
    #pragma unroll
    for (int tt = 0; tt < 2; ++tt)
        #pragma unroll
        for (int i = 0; i < 4; ++i) {
            int qr = qb0 + tt * 64 + g * 4 + i;
            cx[tt][i] = coords[qr * 2] * CSC; cy[tt][i] = coords[qr * 2 + 1] * CSC;
        }

    float l_i[2][4] = {{0.f,0.f,0.f,0.f},{0.f,0.f,0.f,0.f}};
    f32x4 O0[8], O1[8];
    #pragma unroll
    for (int c = 0; c < 8; ++c) { O0[c] = (f32x4){0.f,0.f,0.f,0.f}; O1[c] = (f32x4){0.f,0.f,0.f,0.f}; }

    const int kp = t & 15, co = t >> 4;
    const int kgbase = (b << 11) + p * KPP;

    {   // stage tile 0 into buffer 0
        const __bf16* sp = vb + (size_t)(kgbase + 2 * kp) * H_ + co * 8;
        bf16x8 va = *(const bf16x8*)sp;
        bf16x8 vb2 = *(const bf16x8*)(sp + H_);
        ushort8 ua = __builtin_bit_cast(ushort8, va);
        ushort8 ub = __builtin_bit_cast(ushort8, vb2);
        #pragma unroll
        for (int j = 0; j < 8; ++j)
            Vsu[0][co * 8 + j][kp] = (unsigned)ua[j] | ((unsigned)ub[j] << 16);
    }

    for (int kt = 0; kt < NT; ++kt) {
        __syncthreads();

        bf16x8 nva, nvb;
        if (kt + 1 < NT) {
            const __bf16* sp = vb + (size_t)(kgbase + (kt + 1) * 32 + 2 * kp) * H_ + co * 8;
            nva = *(const bf16x8*)sp;
            nvb = *(const bf16x8*)(sp + H_);
        }

        const int kg = kgbase + kt * 32;
        #pragma unroll
        for (int mt = 0; mt < 2; ++mt) {
            bf16x8 kf[4];
            const __bf16* krow = kb + (size_t)(kg + mt * 16 + l16) * H_;
            #pragma unroll
            for (int kk = 0; kk < 4; ++kk) kf[kk] = *(const bf16x8*)(krow + kk * 32 + g * 8);

            f32x4 acc0 = {0.f,0.f,0.f,0.f}, acc1 = {0.f,0.f,0.f,0.f};
            #pragma unroll
            for (int kk = 0; kk < 4; ++kk)
                acc0 = __builtin_amdgcn_mfma_f32_16x16x32_bf16(qf[0][kk], kf[kk], acc0, 0, 0, 0);
            #pragma unroll
            for (int kk = 0; kk < 4; ++kk)
                acc1 = __builtin_amdgcn_mfma_f32_16x16x32_bf16(qf[1][kk], kf[kk], acc1, 0, 0, 0);

            float2 kc = *(const float2*)&coords[(kg + mt * 16 + l16) * 2];
            const float kx = kc.x * CSC, ky = kc.y * CSC;
            #pragma unroll
            for (int i = 0; i < 4; ++i) {
                float dx = cx[0][i] - kx, dy = cy[0][i] - ky;
                float s = SQRTF_(fmaf(dx, dx, fmaf(dy, dy, 2e-8f)));
                float pe = EXP2F_(acc0[i] + fmaf(fmaf(c2, s, c1), s, c0));
                l_i[0][i] += pe;
                Pl[wid][0][g * 4 + i][mt * 16 + l16] = (__bf16)pe;
            }
            #pragma unroll
            for (int i = 0; i < 4; ++i) {
                float dx = cx[1][i] - kx, dy = cy[1][i] - ky;
                float s = SQRTF_(fmaf(dx, dx, fmaf(dy, dy, 2e-8f)));
                float pe = EXP2F_(acc1[i] + fmaf(fmaf(c2, s, c1), s, c0));
                l_i[1][i] += pe;
                Pl[wid][1][g * 4 + i][mt * 16 + l16] = (__bf16)pe;
            }
        }

        if (kt + 1 < NT) {
            ushort8 ua = __builtin_bit_cast(ushort8, nva);
            ushort8 ub = __builtin_bit_cast(ushort8, nvb);
            #pragma unroll
            for (int j = 0; j < 8; ++j)
                Vsu[(kt + 1) & 1][co * 8 + j][kp] = (unsigned)ua[j] | ((unsigned)ub[j] << 16);
        }

        bf16x8 pf0 = *(const bf16x8*)&Pl[wid][0][l16][g * 8];
        bf16x8 pf1 = *(const bf16x8*)&Pl[wid][1][l16][g * 8];
        #pragma unroll
        for (int c = 0; c < 8; ++c) {
            bf16x8 vf = *(const bf16x8*)&Vsu[kt & 1][c * 16 + l16][g * 4];
            O0[c] = __builtin_amdgcn_mfma_f32_16x16x32_bf16(pf0, vf, O0[c], 0, 0, 0);
            O1[c] = __builtin_amdgcn_mfma_f32_16x16x32_bf16(pf1, vf, O1[c], 0, 0, 0);
        }
    }

    // write partials: u32-packed bf16 row-pairs
    #pragma unroll
    for (int tt = 0; tt < 2; ++tt) {
        const size_t rpbase = (size_t)p * (ROWS_ / 2) + ((qb0 + tt * 64) >> 1) + g * 2;
        #pragma unroll
        for (int c = 0; c < 8; ++c)
            #pragma unroll
            for (int ip = 0; ip < 2; ++ip) {
                float lo_f = tt ? O1[c][2 * ip]     : O0[c][2 * ip];
                float hi_f = tt ? O1[c][2 * ip + 1] : O0[c][2 * ip + 1];
                unsigned lo = __builtin_bit_cast(unsigned, lo_f);
                unsigned hi = __builtin_bit_cast(unsigned, hi_f);
                Opb32[(rpbase + ip) * H_ + c * 16 + l16] = (hi & 0xffff0000u) | (lo >> 16);
            }
    }
    #pragma unroll
    for (int tt = 0; tt < 2; ++tt)
        #pragma unroll
        for (int i = 0; i < 4; ++i) {
            float lv = l_i[tt][i];
            lv += __shfl_xor(lv, 1); lv += __shfl_xor(lv, 2);
            lv += __shfl_xor(lv, 4); lv += __shfl_xor(lv, 8);
            if (l16 == 0) Larr[(qb0 + tt * 64 + g * 4 + i) * KSP + p] = lv;
        }
}

// ---------------- Kernel 3: combine + out-proj + silu + residual + LN ----------------
template<int KSP>
__global__ __launch_bounds__(256) void final_kernel(
    const unsigned int* __restrict__ Opb32, const float* __restrict__ Larr,
    const float* __restrict__ h, const float* __restrict__ Wo, const float* __restrict__ bo,
    const float* __restrict__ gamma, const float* __restrict__ beta, float* __restrict__ out)
{
    __shared__ __align__(16) float as_[8][128];
    __shared__ float redS[4][4], redQ[4][4];
    const int t = threadIdx.x;
    const int c = t & 127;
    const int rh = t >> 7;                 // row half 0/1
    const int bx = blockIdx.x;
    const int row0 = (bx & 31) * 128 + (bx >> 5) * 8;

    // combine KSP key-partition partials, 2 row-pairs per thread
    #pragma unroll
    for (int pr = 0; pr < 2; ++pr) {
        int r0 = rh * 4 + pr * 2;          // even local row
        int row = row0 + r0;
        size_t rp = (size_t)row >> 1;
        float accL = 0.f, accH = 0.f, lsumL = 0.f, lsumH = 0.f;
        #pragma unroll
        for (int p = 0; p < KSP; ++p) {
            unsigned v = Opb32[((size_t)p * (ROWS_ / 2) + rp) * H_ + c];
            accL += __uint_as_float(v << 16);
            accH += __uint_as_float(v & 0xffff0000u);
        }
        #pragma unroll
        for (int q4 = 0; q4 < KSP / 4; ++q4) {
            f32x4 lL = *(const f32x4*)&Larr[row * KSP + q4 * 4];
            f32x4 lH = *(const f32x4*)&Larr[(row + 1) * KSP + q4 * 4];
            lsumL += lL[0] + lL[1] + lL[2] + lL[3];
            lsumH += lH[0] + lH[1] + lH[2] + lH[3];
        }
        as_[r0][c]     = accL / lsumL;
        as_[r0 + 1][c] = accH / lsumH;
    }
    __syncthreads();

    // out-projection: 4 rows per thread
    float acc4[4] = {0.f, 0.f, 0.f, 0.f};
    #pragma unroll 4
    for (int d4 = 0; d4 < 32; ++d4) {
        float w0 = Wo[(d4 * 4 + 0) * 128 + c];
        float w1 = Wo[(d4 * 4 + 1) * 128 + c];
        float w2 = Wo[(d4 * 4 + 2) * 128 + c];
        float w3 = Wo[(d4 * 4 + 3) * 128 + c];
        #pragma unroll
        for (int r = 0; r < 4; ++r) {
            f32x4 a_ = *(const f32x4*)&as_[rh * 4 + r][d4 * 4];
            acc4[r] = fmaf(a_[0], w0, acc4[r]);
            acc4[r] = fmaf(a_[1], w1, acc4[r]);
            acc4[r] = fmaf(a_[2], w2, acc4[r]);
            acc4[r] = fmaf(a_[3], w3, acc4[r]);
        }
    }

    const float bov = bo[c], gv = gamma[c], bvv = beta[c];
    const int wv = t >> 6;                 // wave index 0..3
    float res[4];
    #pragma unroll
    for (int r = 0; r < 4; ++r) {
        float x = acc4[r] + bov;
        float sl = x / (1.f + __expf(-x));
        res[r] = h[(size_t)(row0 + rh * 4 + r) * 128 + c] + sl;
    }

    #pragma unroll
    for (int r = 0; r < 4; ++r) {
        float s1 = res[r], s2 = res[r] * res[r];
        #pragma unroll
        for (int off = 32; off >= 1; off >>= 1) {
            s1 += __shfl_xor(s1, off);
            s2 += __shfl_xor(s2, off);
        }
        if ((t & 63) == 0) { redS[wv][r] = s1; redQ[wv][r] = s2; }
    }
    __syncthreads();
    #pragma unroll
    for (int r = 0; r < 4; ++r) {
        float sum = redS[2 * rh][r] + redS[2 * rh + 1][r];
        float sq  = redQ[2 * rh][r] + redQ[2 * rh + 1][r];
        float mu  = sum * (1.f / 128.f);
        float var = sq * (1.f / 128.f) - mu * mu;
        out[(size_t)(row0 + rh * 4 + r) * 128 + c] = (res[r] - mu) * rsqrtf(var + 1e-5f) * gv + bvv;
    }
}

extern "C" void kernel_launch(void* const* d_in, const int* in_sizes, int n_in,
                              void* d_out, int out_size, void* d_ws, size_t ws_size,
                              hipStream_t stream)
{
    const float* h      = (const float*)d_in[0];
    const float* coords = (const float*)d_in[1];
    const float* Wq = (const float*)d_in[2];  const float* bq = (const float*)d_in[3];
    const float* Wk = (const float*)d_in[4];  const float* bk = (const float*)d_in[5];
    const float* Wv = (const float*)d_in[6];  const float* bv = (const float*)d_in[7];
    const float* Wd1 = (const float*)d_in[8]; const float* bd1 = (const float*)d_in[9];
    const float* Wd2 = (const float*)d_in[10];const float* bd2 = (const float*)d_in[11];
    const float* Wo = (const float*)d_in[12]; const float* bo = (const float*)d_in[13];
    const float* gamma = (const float*)d_in[14]; const float* beta = (const float*)d_in[15];

    char* ws = (char*)d_ws;
    __bf16* qb = (__bf16*)(ws + Q_OFF);
    __bf16* kb = (__bf16*)(ws + K_OFF);
    __bf16* vb = (__bf16*)(ws + V_OFF);
    float* cf           = (float*)(ws + CF_OFF);
    float* Larr         = (float*)(ws + L_OFF);
    unsigned int* Opb32 = (unsigned int*)(ws + OP_OFF);

    const size_t need32 = (size_t)OP_OFF + (size_t)32 * (ROWS_ / 2) * H_ * 4;
    const bool big = ws_size >= need32;

    qkv_mfma<<<dim3(64, 12), 256, 0, stream>>>(h, Wq, bq, Wk, bk, Wv, bv,
                                               Wd1, bd1, Wd2, bd2, qb, kb, vb, cf);
    if (big) {
        attn_kernel<32><<<dim3(32, 32), 256, 0, stream>>>(qb, kb, vb, coords, cf, Opb32, Larr);
        final_kernel<32><<<ROWS_ / 8, 256, 0, stream>>>(Opb32, Larr, h, Wo, bo, gamma, beta, (float*)d_out);
    } else {
        attn_kernel<16><<<dim3(16, 32), 256, 0, stream>>>(qb, kb, vb, coords, cf, Opb32, Larr);
        final_kernel<16><<<ROWS_ / 8, 256, 0, stream>>>(Opb32, Larr, h, Wo, bo, gamma, beta, (float*)d_out);
    }
}

// Round 20
// 47.314 us; speedup vs baseline: 2.3060x; 1.0210x over previous
//
#include <hip/hip_runtime.h>
#include <hip/hip_bf16.h>

#define B_ 2
#define N_ 2048
#define D_ 128
#define H_ 128
#define ROWS_ (B_*N_)               // 4096
#define DMAX_ 1.4143f
#define SCALE_ 0.08838834764831845f // 1/sqrt(128)
#define LOG2E_ 1.4426950408889634f

typedef __bf16 bf16x8 __attribute__((ext_vector_type(8)));
typedef float  f32x4  __attribute__((ext_vector_type(4)));
typedef unsigned short ushort8 __attribute__((ext_vector_type(8)));

#if __has_builtin(__builtin_amdgcn_exp2f)
#define EXP2F_ __builtin_amdgcn_exp2f
#else
#define EXP2F_ exp2f
#endif
#if __has_builtin(__builtin_amdgcn_sqrtf)
#define SQRTF_ __builtin_amdgcn_sqrtf
#else
#define SQRTF_ sqrtf
#endif

// ---- workspace layout (bytes); OP region sized at host per ws_size ----
#define Q_OFF    0
#define K_OFF    (ROWS_*H_*2)                // 1 MB each
#define V_OFF    (2*ROWS_*H_*2)
#define CF_OFF   (3*ROWS_*H_*2)              // 64 B quadratic coeffs
#define L_OFF    (CF_OFF + 64)               // up to 512 KB (l partials, KS<=32)
#define OP_OFF   (L_OFF + ROWS_*32*4)        // u32-packed partial O (KS * 1.05 MB)

// ---------------- Kernel 1: QKV projection via MFMA (W transposed in-block) ----------------
// grid (64, 12): which = y>>2 selects q/k/v, c0 = (y&3)*32 output cols; 64 rows/block.
__global__ __launch_bounds__(256) void qkv_mfma(
    const float* __restrict__ h,
    const float* __restrict__ Wq, const float* __restrict__ bq,
    const float* __restrict__ Wk, const float* __restrict__ bk,
    const float* __restrict__ Wv, const float* __restrict__ bv,
    const float* __restrict__ Wd1, const float* __restrict__ bd1,
    const float* __restrict__ Wd2, const float* __restrict__ bd2,
    __bf16* __restrict__ qb, __bf16* __restrict__ kb, __bf16* __restrict__ vb,
    float* __restrict__ cf)
{
    __shared__ __align__(16) __bf16 Wl[32][144];
    const int t = threadIdx.x;
    const int y = blockIdx.y;
    const int which = y >> 2, c0 = (y & 3) * 32;
    const float* W    = which == 0 ? Wq : (which == 1 ? Wk : Wv);
    const float* bias = which == 0 ? bq : (which == 1 ? bk : bv);
    __bf16* outp      = which == 0 ? qb : (which == 1 ? kb : vb);
    const float scale = which == 0 ? (SCALE_ * LOG2E_) : 1.f;

    if (blockIdx.x == 0 && y == 0 && t < 64) {
        // quadratic Lagrange fit of log2e*g(d) at nodes d = {0, DMAX/2, DMAX}
        // (silu has no x^3 term; x^4 residual ~1e-7 -> g(d) is numerically quadratic)
        const int j = t & 31;
        const float w1 = Wd1[j], b1 = bd1[j];
        const float w2h = Wd2[j] * 0.5f;        // lanes 32..63 duplicate -> half weight
        float gv[3];
        #pragma unroll
        for (int i = 0; i < 3; ++i) {
            float d = (DMAX_ * 0.5f) * (float)i;
            float x = fmaf(d, w1, b1);
            gv[i] = (x / (1.f + __expf(-x))) * w2h;
        }
        #pragma unroll
        for (int i = 0; i < 3; ++i)
            #pragma unroll
            for (int off = 1; off < 64; off <<= 1) gv[i] += __shfl_xor(gv[i], off);
        if (t == 0) {
            const float bd2v = bd2[0];
            float g0 = (gv[0] + bd2v) * LOG2E_, g1 = (gv[1] + bd2v) * LOG2E_,
                  g2 = (gv[2] + bd2v) * LOG2E_;
            cf[0] = g0;                                   // bias(s) = c0 + c1 s + c2 s^2,
            cf[1] = -1.5f * g0 + 2.f * g1 - 0.5f * g2;    // s = dist * 2/DMAX in [0,2]
            cf[2] =  0.5f * g0 - g1 + 0.5f * g2;
        }
    }

    // stage W slice [128 k][32 c] -> Wl[c][k] bf16
    #pragma unroll
    for (int i = 0; i < 16; ++i) {
        int idx = t + i * 256, k = idx >> 5, cc = idx & 31;
        Wl[cc][k] = (__bf16)W[k * 128 + c0 + cc];
    }
    __syncthreads();

    const int wid = t >> 6, lane = t & 63, l16 = lane & 15, g = lane >> 4;
    const int row0 = blockIdx.x * 64 + wid * 16;

    bf16x8 af[4];
    const float* arow = h + (size_t)(row0 + l16) * 128;
    #pragma unroll
    for (int kk = 0; kk < 4; ++kk) {
        float4 a0 = *(const float4*)(arow + kk * 32 + g * 8);
        float4 a1 = *(const float4*)(arow + kk * 32 + g * 8 + 4);
        af[kk] = (bf16x8){ (__bf16)a0.x, (__bf16)a0.y, (__bf16)a0.z, (__bf16)a0.w,
                           (__bf16)a1.x, (__bf16)a1.y, (__bf16)a1.z, (__bf16)a1.w };
    }

    f32x4 acc0 = {0.f,0.f,0.f,0.f}, acc1 = {0.f,0.f,0.f,0.f};
    #pragma unroll
    for (int kk = 0; kk < 4; ++kk) {
        bf16x8 f0 = *(const bf16x8*)&Wl[l16][kk * 32 + g * 8];
        acc0 = __builtin_amdgcn_mfma_f32_16x16x32_bf16(af[kk], f0, acc0, 0, 0, 0);
    }
    #pragma unroll
    for (int kk = 0; kk < 4; ++kk) {
        bf16x8 f1 = *(const bf16x8*)&Wl[16 + l16][kk * 32 + g * 8];
        acc1 = __builtin_amdgcn_mfma_f32_16x16x32_bf16(af[kk], f1, acc1, 0, 0, 0);
    }
    const float bv0 = bias[c0 + l16], bv1 = bias[c0 + 16 + l16];
    #pragma unroll
    for (int i = 0; i < 4; ++i) {
        size_t r = (size_t)(row0 + g * 4 + i) * 128;
        outp[r + c0 + l16]      = (__bf16)((acc0[i] + bv0) * scale);
        outp[r + c0 + 16 + l16] = (__bf16)((acc1[i] + bv1) * scale);
    }
}

// ---------------- Kernel 2: flash attention, 2 q-tiles per wave, templated KS ----------------
// grid (32, KSP): block owns 128 q-rows x one key partition. 3 blocks/CU (bounds-4 spilled: r11).
template<int KSP>
__global__ __launch_bounds__(256, 3) void attn_kernel(
    const __bf16* __restrict__ qb, const __bf16* __restrict__ kb, const __bf16* __restrict__ vb,
    const float* __restrict__ coords, const float* __restrict__ cfp,
    unsigned int* __restrict__ Opb32, float* __restrict__ Larr)
{
    constexpr int KPP = N_ / KSP;
    constexpr int NT  = KPP / 32;
    constexpr float CSC = 2.0f / DMAX_;     // coord prescale; s = dist*2/DMAX

    __shared__ __align__(16) unsigned int Vsu[2][128][20];
    __shared__ __align__(16) __bf16 Pl[4][2][16][40];

    const int t    = threadIdx.x;
    const int wid  = t >> 6;
    const int lane = t & 63;
    const int l16  = lane & 15;
    const int g    = lane >> 4;
    const int qb0  = blockIdx.x * 128 + wid * 16;   // tile0 base; tile1 = +64
    const int p    = blockIdx.y;
    const int b    = blockIdx.x >> 4;               // 16 blocks per batch

    const float c0 = cfp[0], c1 = cfp[1], c2 = cfp[2];

    bf16x8 qf[2][4];
    #pragma unroll
    for (int tt = 0; tt < 2; ++tt) {
        const __bf16* qrow = qb + (size_t)(qb0 + tt * 64 + l16) * H_;
        #pragma unroll
        for (int kk = 0; kk < 4; ++kk) qf[tt][kk] = *(const bf16x8*)(qrow + kk * 32 + g * 8);
    }

    float cx[2][4], cy[2][4];
    #pragma unroll
    for (int tt = 0; tt < 2; ++tt)
        #pragma unroll
        for (int i = 0; i < 4; ++i) {
            int qr = qb0 + tt * 64 + g * 4 + i;
            cx[tt][i] = coords[qr * 2] * CSC; cy[tt][i] = coords[qr * 2 + 1] * CSC;
        }

    float l_i[2][4] = {{0.f,0.f,0.f,0.f},{0.f,0.f,0.f,0.f}};
    f32x4 O0[8], O1[8];
    #pragma unroll
    for (int c = 0; c < 8; ++c) { O0[c] = (f32x4){0.f,0.f,0.f,0.f}; O1[c] = (f32x4){0.f,0.f,0.f,0.f}; }

    const int kp = t & 15, co = t >> 4;
    const int kgbase = (b << 11) + p * KPP;

    {   // stage tile 0 into buffer 0
        const __bf16* sp = vb + (size_t)(kgbase + 2 * kp) * H_ + co * 8;
        bf16x8 va = *(const bf16x8*)sp;
        bf16x8 vb2 = *(const bf16x8*)(sp + H_);
        ushort8 ua = __builtin_bit_cast(ushort8, va);
        ushort8 ub = __builtin_bit_cast(ushort8, vb2);
        #pragma unroll
        for (int j = 0; j < 8; ++j)
            Vsu[0][co * 8 + j][kp] = (unsigned)ua[j] | ((unsigned)ub[j] << 16);
    }

    for (int kt = 0; kt < NT; ++kt) {
        __syncthreads();

        bf16x8 nva, nvb;
        if (kt + 1 < NT) {
            const __bf16* sp = vb + (size_t)(kgbase + (kt + 1) * 32 + 2 * kp) * H_ + co * 8;
            nva = *(const bf16x8*)sp;
            nvb = *(const bf16x8*)(sp + H_);
        }

        const int kg = kgbase + kt * 32;
        #pragma unroll
        for (int mt = 0; mt < 2; ++mt) {
            bf16x8 kf[4];
            const __bf16* krow = kb + (size_t)(kg + mt * 16 + l16) * H_;
            #pragma unroll
            for (int kk = 0; kk < 4; ++kk) kf[kk] = *(const bf16x8*)(krow + kk * 32 + g * 8);

            f32x4 acc0 = {0.f,0.f,0.f,0.f}, acc1 = {0.f,0.f,0.f,0.f};
            #pragma unroll
            for (int kk = 0; kk < 4; ++kk)
                acc0 = __builtin_amdgcn_mfma_f32_16x16x32_bf16(qf[0][kk], kf[kk], acc0, 0, 0, 0);
            #pragma unroll
            for (int kk = 0; kk < 4; ++kk)
                acc1 = __builtin_amdgcn_mfma_f32_16x16x32_bf16(qf[1][kk], kf[kk], acc1, 0, 0, 0);

            float2 kc = *(const float2*)&coords[(kg + mt * 16 + l16) * 2];
            const float kx = kc.x * CSC, ky = kc.y * CSC;
            #pragma unroll
            for (int i = 0; i < 4; ++i) {
                float dx = cx[0][i] - kx, dy = cy[0][i] - ky;
                float s = SQRTF_(fmaf(dx, dx, fmaf(dy, dy, 2e-8f)));
                float pe = EXP2F_(acc0[i] + fmaf(fmaf(c2, s, c1), s, c0));
                l_i[0][i] += pe;
                Pl[wid][0][g * 4 + i][mt * 16 + l16] = (__bf16)pe;
            }
            #pragma unroll
            for (int i = 0; i < 4; ++i) {
                float dx = cx[1][i] - kx, dy = cy[1][i] - ky;
                float s = SQRTF_(fmaf(dx, dx, fmaf(dy, dy, 2e-8f)));
                float pe = EXP2F_(acc1[i] + fmaf(fmaf(c2, s, c1), s, c0));
                l_i[1][i] += pe;
                Pl[wid][1][g * 4 + i][mt * 16 + l16] = (__bf16)pe;
            }
        }

        if (kt + 1 < NT) {
            ushort8 ua = __builtin_bit_cast(ushort8, nva);
            ushort8 ub = __builtin_bit_cast(ushort8, nvb);
            #pragma unroll
            for (int j = 0; j < 8; ++j)
                Vsu[(kt + 1) & 1][co * 8 + j][kp] = (unsigned)ua[j] | ((unsigned)ub[j] << 16);
        }

        bf16x8 pf0 = *(const bf16x8*)&Pl[wid][0][l16][g * 8];
        bf16x8 pf1 = *(const bf16x8*)&Pl[wid][1][l16][g * 8];
        #pragma unroll
        for (int c = 0; c < 8; ++c) {
            bf16x8 vf = *(const bf16x8*)&Vsu[kt & 1][c * 16 + l16][g * 4];
            O0[c] = __builtin_amdgcn_mfma_f32_16x16x32_bf16(pf0, vf, O0[c], 0, 0, 0);
            O1[c] = __builtin_amdgcn_mfma_f32_16x16x32_bf16(pf1, vf, O1[c], 0, 0, 0);
        }
    }

    // write partials: u32-packed bf16 row-pairs
    #pragma unroll
    for (int tt = 0; tt < 2; ++tt) {
        const size_t rpbase = (size_t)p * (ROWS_ / 2) + ((qb0 + tt * 64) >> 1) + g * 2;
        #pragma unroll
        for (int c = 0; c < 8; ++c)
            #pragma unroll
            for (int ip = 0; ip < 2; ++ip) {
                float lo_f = tt ? O1[c][2 * ip]     : O0[c][2 * ip];
                float hi_f = tt ? O1[c][2 * ip + 1] : O0[c][2 * ip + 1];
                unsigned lo = __builtin_bit_cast(unsigned, lo_f);
                unsigned hi = __builtin_bit_cast(unsigned, hi_f);
                Opb32[(rpbase + ip) * H_ + c * 16 + l16] = (hi & 0xffff0000u) | (lo >> 16);
            }
    }
    #pragma unroll
    for (int tt = 0; tt < 2; ++tt)
        #pragma unroll
        for (int i = 0; i < 4; ++i) {
            float lv = l_i[tt][i];
            lv += __shfl_xor(lv, 1); lv += __shfl_xor(lv, 2);
            lv += __shfl_xor(lv, 4); lv += __shfl_xor(lv, 8);
            if (l16 == 0) Larr[(qb0 + tt * 64 + g * 4 + i) * KSP + p] = lv;
        }
}

// ---------------- Kernel 3: combine + out-proj + silu + residual + LN ----------------
template<int KSP>
__global__ __launch_bounds__(256) void final_kernel(
    const unsigned int* __restrict__ Opb32, const float* __restrict__ Larr,
    const float* __restrict__ h, const float* __restrict__ Wo, const float* __restrict__ bo,
    const float* __restrict__ gamma, const float* __restrict__ beta, float* __restrict__ out)
{
    __shared__ __align__(16) float as_[8][128];
    __shared__ float redS[4][4], redQ[4][4];
    const int t = threadIdx.x;
    const int c = t & 127;
    const int rh = t >> 7;                 // row half 0/1
    // XCD-affinity: attn block (x,p) lands on XCD x%8 (grid x=32); match bx%8==x%8
    const int bx = blockIdx.x;
    const int row0 = (bx & 31) * 128 + (bx >> 5) * 8;

    // combine KSP key-partition partials, 2 row-pairs per thread
    #pragma unroll
    for (int pr = 0; pr < 2; ++pr) {
        int r0 = rh * 4 + pr * 2;          // even local row
        int row = row0 + r0;
        size_t rp = (size_t)row >> 1;
        float accL = 0.f, accH = 0.f, lsumL = 0.f, lsumH = 0.f;
        #pragma unroll
        for (int p = 0; p < KSP; ++p) {
            unsigned v = Opb32[((size_t)p * (ROWS_ / 2) + rp) * H_ + c];
            accL += __uint_as_float(v << 16);
            accH += __uint_as_float(v & 0xffff0000u);
        }
        #pragma unroll
        for (int q4 = 0; q4 < KSP / 4; ++q4) {
            f32x4 lL = *(const f32x4*)&Larr[row * KSP + q4 * 4];
            f32x4 lH = *(const f32x4*)&Larr[(row + 1) * KSP + q4 * 4];
            lsumL += lL[0] + lL[1] + lL[2] + lL[3];
            lsumH += lH[0] + lH[1] + lH[2] + lH[3];
        }
        as_[r0][c]     = accL / lsumL;
        as_[r0 + 1][c] = accH / lsumH;
    }
    __syncthreads();

    // out-projection: 4 rows per thread
    float acc4[4] = {0.f, 0.f, 0.f, 0.f};
    #pragma unroll 4
    for (int d4 = 0; d4 < 32; ++d4) {
        float w0 = Wo[(d4 * 4 + 0) * 128 + c];
        float w1 = Wo[(d4 * 4 + 1) * 128 + c];
        float w2 = Wo[(d4 * 4 + 2) * 128 + c];
        float w3 = Wo[(d4 * 4 + 3) * 128 + c];
        #pragma unroll
        for (int r = 0; r < 4; ++r) {
            f32x4 a_ = *(const f32x4*)&as_[rh * 4 + r][d4 * 4];
            acc4[r] = fmaf(a_[0], w0, acc4[r]);
            acc4[r] = fmaf(a_[1], w1, acc4[r]);
            acc4[r] = fmaf(a_[2], w2, acc4[r]);
            acc4[r] = fmaf(a_[3], w3, acc4[r]);
        }
    }

    const float bov = bo[c], gv = gamma[c], bvv = beta[c];
    const int wv = t >> 6;                 // wave index 0..3
    float res[4];
    #pragma unroll
    for (int r = 0; r < 4; ++r) {
        float x = acc4[r] + bov;
        float sl = x / (1.f + __expf(-x));
        res[r] = h[(size_t)(row0 + rh * 4 + r) * 128 + c] + sl;
    }

    #pragma unroll
    for (int r = 0; r < 4; ++r) {
        float s1 = res[r], s2 = res[r] * res[r];
        #pragma unroll
        for (int off = 32; off >= 1; off >>= 1) {
            s1 += __shfl_xor(s1, off);
            s2 += __shfl_xor(s2, off);
        }
        if ((t & 63) == 0) { redS[wv][r] = s1; redQ[wv][r] = s2; }
    }
    __syncthreads();
    #pragma unroll
    for (int r = 0; r < 4; ++r) {
        float sum = redS[2 * rh][r] + redS[2 * rh + 1][r];
        float sq  = redQ[2 * rh][r] + redQ[2 * rh + 1][r];
        float mu  = sum * (1.f / 128.f);
        float var = sq * (1.f / 128.f) - mu * mu;
        out[(size_t)(row0 + rh * 4 + r) * 128 + c] = (res[r] - mu) * rsqrtf(var + 1e-5f) * gv + bvv;
    }
}

extern "C" void kernel_launch(void* const* d_in, const int* in_sizes, int n_in,
                              void* d_out, int out_size, void* d_ws, size_t ws_size,
                              hipStream_t stream)
{
    const float* h      = (const float*)d_in[0];
    const float* coords = (const float*)d_in[1];
    const float* Wq = (const float*)d_in[2];  const float* bq = (const float*)d_in[3];
    const float* Wk = (const float*)d_in[4];  const float* bk = (const float*)d_in[5];
    const float* Wv = (const float*)d_in[6];  const float* bv = (const float*)d_in[7];
    const float* Wd1 = (const float*)d_in[8]; const float* bd1 = (const float*)d_in[9];
    const float* Wd2 = (const float*)d_in[10];const float* bd2 = (const float*)d_in[11];
    const float* Wo = (const float*)d_in[12]; const float* bo = (const float*)d_in[13];
    const float* gamma = (const float*)d_in[14]; const float* beta = (const float*)d_in[15];

    char* ws = (char*)d_ws;
    __bf16* qb = (__bf16*)(ws + Q_OFF);
    __bf16* kb = (__bf16*)(ws + K_OFF);
    __bf16* vb = (__bf16*)(ws + V_OFF);
    float* cf           = (float*)(ws + CF_OFF);
    float* Larr         = (float*)(ws + L_OFF);
    unsigned int* Opb32 = (unsigned int*)(ws + OP_OFF);

    const size_t need32 = (size_t)OP_OFF + (size_t)32 * (ROWS_ / 2) * H_ * 4;
    const bool big = ws_size >= need32;

    qkv_mfma<<<dim3(64, 12), 256, 0, stream>>>(h, Wq, bq, Wk, bk, Wv, bv,
                                               Wd1, bd1, Wd2, bd2, qb, kb, vb, cf);
    if (big) {
        attn_kernel<32><<<dim3(32, 32), 256, 0, stream>>>(qb, kb, vb, coords, cf, Opb32, Larr);
        final_kernel<32><<<ROWS_ / 8, 256, 0, stream>>>(Opb32, Larr, h, Wo, bo, gamma, beta, (float*)d_out);
    } else {
        attn_kernel<16><<<dim3(32, 16), 256, 0, stream>>>(qb, kb, vb, coords, cf, Opb32, Larr);
        final_kernel<16><<<ROWS_ / 8, 256, 0, stream>>>(Opb32, Larr, h, Wo, bo, gamma, beta, (float*)d_out);
    }
}